// Round 5
// baseline (6014.272 us; speedup 1.0000x reference)
//
#include <hip/hip_runtime.h>

// GRU: T=1024 B=64 D=256 H=512 O=256.
// Round 5 = Round 4 with the asm-load hazard fixed: the consumer poll's
// global_load_dwordx4 dst registers were only guarded by a SEPARATE
// s_waitcnt asm statement; the compiler could (and did) schedule the tag
// checks between the load asm and the wait asm, validating stale register
// contents (h_{t-2}, whose tag matches 7/8 of steps). Fix: loads and the
// trailing s_waitcnt vmcnt(0) live in ONE asm block with early-clobber
// outputs, so no use of the loaded values can precede the wait.

#define T_ 1024
#define B_ 64
#define D_ 256
#define H_ 512
#define G_ 1536
#define O_ 256

typedef __attribute__((ext_vector_type(8))) short short8;
typedef __attribute__((ext_vector_type(4))) short short4v;
typedef __attribute__((ext_vector_type(4))) float float4v;
typedef __attribute__((ext_vector_type(4))) unsigned uint4v;

static __device__ __forceinline__ unsigned short f2b(float f) {
  unsigned u = __builtin_bit_cast(unsigned, f);
  u += 0x7fffu + ((u >> 16) & 1u);          // RNE (finite inputs)
  return (unsigned short)(u >> 16);
}
static __device__ __forceinline__ short b2s(unsigned u) {  // fp32 bits -> bf16 RNE
  u += 0x7fffu + ((u >> 16) & 1u);
  return (short)(u >> 16);
}

// one 16B coherent load with the wait fused into the same asm block
static __device__ __forceinline__ uint4v poll_load16(const float* p) {
  uint4v d;
  asm volatile("global_load_dwordx4 %0, %1, off sc0 sc1\n\t"
               "s_waitcnt vmcnt(0)"
               : "=&v"(d) : "v"(p) : "memory");
  return d;
}

// ---------------------------------------------------------------- prep ------
__global__ __launch_bounds__(256) void prep_kernel(
    const float* __restrict__ x, const float* __restrict__ Wi,
    const float* __restrict__ Wh, const float* __restrict__ Wo,
    unsigned short* __restrict__ xb, unsigned short* __restrict__ WhT,
    unsigned short* __restrict__ WiT, unsigned short* __restrict__ WoT,
    unsigned* __restrict__ hc)
{
  const size_t NXB = (size_t)T_ * B_ * D_;
  const size_t NWH = (size_t)G_ * H_;
  const size_t NWI = (size_t)G_ * D_;
  const size_t NWO = (size_t)O_ * H_;
  const size_t NHC = 262144;                 // 8 slots x 4 groups x 16 x 512
  const size_t NTOT = NXB + NWH + NWI + NWO + NHC;
  size_t i = (size_t)blockIdx.x * blockDim.x + threadIdx.x;
  const size_t stride = (size_t)gridDim.x * blockDim.x;
  for (; i < NTOT; i += stride) {
    if (i < NXB) { xb[i] = f2b(x[i]); continue; }
    size_t j = i - NXB;
    if (j < NWH) { size_t g = j >> 9, k = j & 511; WhT[j] = f2b(Wh[k * G_ + g]); continue; }
    j -= NWH;
    if (j < NWI) { size_t g = j >> 8, k = j & 255; WiT[j] = f2b(Wi[k * G_ + g]); continue; }
    j -= NWI;
    if (j < NWO) { size_t o = j >> 9, k = j & 511; WoT[j] = f2b(Wo[k * O_ + o]); continue; }
    j -= NWO;
    hc[j] = 1u;    // LSB=1: mismatches first-window tag 0 (poison-proof)
  }
}

// ---------------------------------------------------------------- scan ------
// 64 WGs x 384 thr (6 waves). group = wg&3 (16 batch rows), slice = wg>>2
// (32 h-cols). wave -> (gk = wave%3, s = wave/3). Gate waves: gk==0 (waves 0,3).
// Stager waves: gk!=0 (waves 1,2,4,5 -> 256 threads, 8 chunks of 16B each).
__global__ __launch_bounds__(384, 2) void scan_kernel(
    const unsigned short* __restrict__ xb,
    const unsigned short* __restrict__ WhT,
    const unsigned short* __restrict__ WiT,
    unsigned short* __restrict__ hs,
    float* __restrict__ hc,
    const float* __restrict__ bi,
    const float* __restrict__ bhn,
    const float* __restrict__ h0)
{
  const int wg = blockIdx.x;
  const int group = wg & 3;
  const int slice = wg >> 2;
  const int tid = threadIdx.x;
  const int wave = tid >> 6;
  const int lane = tid & 63;
  const int m = lane & 15;
  const int quad = lane >> 4;
  const int gk = wave % 3;
  const int s = wave / 3;
  const bool is_gate = (gk == 0);
  const int sid = is_gate ? 0 : ((((gk - 1) + s * 2) << 6) | lane);  // 0..255
  const int row0 = group * 16;
  const int jbase = slice * 32 + s * 16;
  const int gcol = gk * 512 + jbase + m;

  __shared__ unsigned short hT[16 * 512];   // bf16 h tile, 16B-block XOR swizzle
  __shared__ float lds_h[6][256];
  __shared__ float lds_x[6][256];

  // persistent B fragments (registers)
  short8 Bh[16], Bx[8];
  {
    const unsigned short* p = WhT + (size_t)gcol * H_ + quad * 8;
#pragma unroll
    for (int k = 0; k < 16; ++k) Bh[k] = *(const short8*)(p + k * 32);
    const unsigned short* q = WiT + (size_t)gcol * D_ + quad * 8;
#pragma unroll
    for (int k = 0; k < 8; ++k) Bx[k] = *(const short8*)(q + k * 32);
  }

  const int jcol = jbase + m;
  const float bi_r = bi[jcol];
  const float bi_z = bi[512 + jcol];
  const float bi_n = bi[1024 + jcol];
  const float bhn_c = bhn[jcol];
  float hold[4];
#pragma unroll
  for (int i = 0; i < 4; ++i)
    hold[i] = h0[(size_t)(row0 + quad * 4 + i) * H_ + jcol];

  // x A-fragments for t=0
  short8 xa[8];
  {
    const unsigned short* xp = xb + ((size_t)(row0 + m)) * D_ + quad * 8;
#pragma unroll
    for (int k = 0; k < 8; ++k) xa[k] = *(const short8*)(xp + k * 32);
  }

  for (int t = 0; t < T_; ++t) {
    // ---- stage h_{t-1} -> hT (stager waves only) ----
    if (!is_gate) {
      if (t == 0) {
        const float* src = h0 + (size_t)row0 * H_;
#pragma unroll
        for (int j = 0; j < 8; ++j) {
          const int c = sid + j * 256;
          const int r = c >> 7, q = c & 127;
          float4v d = *(const float4v*)(src + r * H_ + q * 4);
          const int b2 = (q >> 1) ^ (r & 7);
          short4v o = { (short)f2b(d[0]), (short)f2b(d[1]),
                        (short)f2b(d[2]), (short)f2b(d[3]) };
          *(short4v*)&hT[r * 512 + b2 * 8 + (q & 1) * 4] = o;
        }
      } else {
        const unsigned etag = (unsigned)((t - 1) >> 3) & 1u;
        const float* src = hc + (size_t)((((t - 1) & 7) * 4 + group) << 13);
        const float* p0 = src + (size_t)(sid + 0 * 256) * 4;
        const float* p1 = src + (size_t)(sid + 1 * 256) * 4;
        const float* p2 = src + (size_t)(sid + 2 * 256) * 4;
        const float* p3 = src + (size_t)(sid + 3 * 256) * 4;
        const float* p4 = src + (size_t)(sid + 4 * 256) * 4;
        const float* p5 = src + (size_t)(sid + 5 * 256) * 4;
        const float* p6 = src + (size_t)(sid + 6 * 256) * 4;
        const float* p7 = src + (size_t)(sid + 7 * 256) * 4;
        uint4v d[8];
        // all 8 loads + the wait in ONE asm block: no use of d[] can be
        // scheduled before the s_waitcnt. =&v keeps dsts off the addr regs.
        asm volatile(
            "global_load_dwordx4 %0, %8, off sc0 sc1\n\t"
            "global_load_dwordx4 %1, %9, off sc0 sc1\n\t"
            "global_load_dwordx4 %2, %10, off sc0 sc1\n\t"
            "global_load_dwordx4 %3, %11, off sc0 sc1\n\t"
            "global_load_dwordx4 %4, %12, off sc0 sc1\n\t"
            "global_load_dwordx4 %5, %13, off sc0 sc1\n\t"
            "global_load_dwordx4 %6, %14, off sc0 sc1\n\t"
            "global_load_dwordx4 %7, %15, off sc0 sc1\n\t"
            "s_waitcnt vmcnt(0)"
            : "=&v"(d[0]), "=&v"(d[1]), "=&v"(d[2]), "=&v"(d[3]),
              "=&v"(d[4]), "=&v"(d[5]), "=&v"(d[6]), "=&v"(d[7])
            : "v"(p0), "v"(p1), "v"(p2), "v"(p3),
              "v"(p4), "v"(p5), "v"(p6), "v"(p7)
            : "memory");
        unsigned bad = 0;
#pragma unroll
        for (int j = 0; j < 8; ++j)
          if (((d[j].x ^ etag) | (d[j].y ^ etag) | (d[j].z ^ etag) |
               (d[j].w ^ etag)) & 1u) bad |= 1u << j;
        while (bad) {
          __builtin_amdgcn_s_sleep(1);
#pragma unroll
          for (int j = 0; j < 8; ++j) if (bad & (1u << j)) {
            const float* p = src + (size_t)(sid + j * 256) * 4;
            uint4v nd = poll_load16(p);   // load+wait fused in one asm block
            if (!(((nd.x ^ etag) | (nd.y ^ etag) | (nd.z ^ etag) |
                   (nd.w ^ etag)) & 1u)) { d[j] = nd; bad &= ~(1u << j); }
          }
        }
#pragma unroll
        for (int j = 0; j < 8; ++j) {
          const int c = sid + j * 256;
          const int r = c >> 7, q = c & 127;
          const int b2 = (q >> 1) ^ (r & 7);
          short4v o = { b2s(d[j].x), b2s(d[j].y), b2s(d[j].z), b2s(d[j].w) };
          *(short4v*)&hT[r * 512 + b2 * 8 + (q & 1) * 4] = o;
        }
      }
    }
    __syncthreads();   // B1: hT staged; prev-step gates done

    // ---- MFMAs (all waves) ----
    float4v acch = {0.f, 0.f, 0.f, 0.f};
    float4v accx = {0.f, 0.f, 0.f, 0.f};
#pragma unroll
    for (int k = 0; k < 16; ++k) {
      const int b2 = (k * 4 + quad) ^ (m & 7);
      short8 a = *(const short8*)&hT[m * 512 + b2 * 8];
      acch = __builtin_amdgcn_mfma_f32_16x16x32_bf16(a, Bh[k], acch, 0, 0, 0);
    }
#pragma unroll
    for (int k = 0; k < 8; ++k)
      accx = __builtin_amdgcn_mfma_f32_16x16x32_bf16(xa[k], Bx[k], accx, 0, 0, 0);

    // exchange pre-activations
#pragma unroll
    for (int i = 0; i < 4; ++i) {
      const int idx = (quad * 4 + i) * 16 + m;
      lds_h[wave][idx] = acch[i];
      lds_x[wave][idx] = accx[i];
    }
    // prefetch x A-frags for t+1 (in flight across the barrier)
    if (t + 1 < T_) {
      const unsigned short* xp = xb + ((size_t)(t + 1) * B_ + row0 + m) * D_ + quad * 8;
#pragma unroll
      for (int k = 0; k < 8; ++k) xa[k] = *(const short8*)(xp + k * 32);
    }
    __syncthreads();   // B2: lds_h/lds_x ready

    if (is_gate) {
      const int wb = s * 3;
      const unsigned tag = (unsigned)(t >> 3) & 1u;
      float* dstc = hc + (size_t)(((t & 7) * 4 + group) << 13);
#pragma unroll
      for (int i = 0; i < 4; ++i) {
        const int r = quad * 4 + i;
        const int idx = r * 16 + m;
        const float pr = lds_h[wb + 0][idx] + lds_x[wb + 0][idx] + bi_r;
        const float pz = lds_h[wb + 1][idx] + lds_x[wb + 1][idx] + bi_z;
        const float pn = lds_x[wb + 2][idx] + bi_n;
        const float rg = __builtin_amdgcn_rcpf(1.f + __expf(-pr));
        const float zg = __builtin_amdgcn_rcpf(1.f + __expf(-pz));
        const float an = pn + rg * (lds_h[wb + 2][idx] + bhn_c);
        const float ng = 2.f * __builtin_amdgcn_rcpf(1.f + __expf(-2.f * an)) - 1.f;
        const float hn = (1.f - zg) * ng + zg * hold[i];
        hold[i] = hn;
        // tagged fp32 -> hc (sc0sc1 write-through to coherence point)
        unsigned u = (__builtin_bit_cast(unsigned, hn) & ~1u) | tag;
        float* p = dstc + r * 512 + jcol;
        asm volatile("global_store_dword %0, %1, off sc0 sc1"
                     :: "v"(p), "v"(u) : "memory");
        // bf16 -> hs for the output GEMM (plain store, flushed at kernel end)
        hs[((size_t)t * B_ + row0 + r) * H_ + jcol] = (unsigned short)b2s(
            __builtin_bit_cast(unsigned, hn));
      }
      // drain this step's stores before starting the next step (slot occupancy
      // strictly sequential; overlaps the consumers' poll latency).
      asm volatile("s_waitcnt vmcnt(0)" ::: "memory");
    }
    // stagers loop around and immediately start polling hc[t&7]
  }
}

// ---------------------------------------------------------------- ogemm -----
__global__ __launch_bounds__(256) void ogemm_kernel(
    const unsigned short* __restrict__ hs, const unsigned short* __restrict__ WoT,
    const float* __restrict__ bo, float* __restrict__ out)
{
  const int wv = threadIdx.x >> 6, lane = threadIdx.x & 63;
  const int m = lane & 15, quad = lane >> 4;
  const int rowbase = blockIdx.x * 64 + wv * 16;
  const unsigned short* ap = hs + (size_t)(rowbase + m) * H_ + quad * 8;
  float4v acc[16];
#pragma unroll
  for (int n = 0; n < 16; ++n) { float4v z = {0.f,0.f,0.f,0.f}; acc[n] = z; }
#pragma unroll
  for (int k = 0; k < 16; ++k) {
    short8 a = *(const short8*)(ap + k * 32);
#pragma unroll
    for (int n = 0; n < 16; ++n) {
      short8 b = *(const short8*)(WoT + (size_t)(n * 16 + m) * H_ + k * 32 + quad * 8);
      acc[n] = __builtin_amdgcn_mfma_f32_16x16x32_bf16(a, b, acc[n], 0, 0, 0);
    }
  }
#pragma unroll
  for (int n = 0; n < 16; ++n) {
    const int col = n * 16 + m;
    const float bias = bo[col];
#pragma unroll
    for (int i = 0; i < 4; ++i) {
      const int r = rowbase + quad * 4 + i;
      out[(size_t)r * O_ + col] = acc[n][i] + bias;
    }
  }
}

// ---------------------------------------------------------------- launch ----
extern "C" void kernel_launch(void* const* d_in, const int* in_sizes, int n_in,
                              void* d_out, int out_size, void* d_ws, size_t ws_size,
                              hipStream_t stream)
{
  const float* x   = (const float*)d_in[0];
  const float* Wi  = (const float*)d_in[1];
  const float* bi  = (const float*)d_in[2];
  const float* Wh  = (const float*)d_in[3];
  const float* bhn = (const float*)d_in[4];
  const float* Wo  = (const float*)d_in[5];
  const float* bo  = (const float*)d_in[6];
  const float* h0  = (const float*)d_in[7];
  float* out = (float*)d_out;

  char* ws = (char*)d_ws;
  unsigned short* xb  = (unsigned short*)ws;  ws += (size_t)T_ * B_ * D_ * 2;  // 33.5 MB
  unsigned short* WhT = (unsigned short*)ws;  ws += (size_t)G_ * H_ * 2;       // 1.5 MB
  unsigned short* WiT = (unsigned short*)ws;  ws += (size_t)G_ * D_ * 2;       // 0.75 MB
  unsigned short* WoT = (unsigned short*)ws;  ws += (size_t)O_ * H_ * 2;       // 0.25 MB
  unsigned short* hs  = (unsigned short*)ws;  ws += (size_t)T_ * B_ * H_ * 2;  // 67 MB
  float* hc           = (float*)ws;                                             // 1 MB

  prep_kernel<<<4096, 256, 0, stream>>>(x, Wi, Wh, Wo, xb, WhT, WiT, WoT,
                                        (unsigned*)hc);
  scan_kernel<<<64, 384, 0, stream>>>(xb, WhT, WiT, hs, hc, bi, bhn, h0);
  ogemm_kernel<<<1024, 256, 0, stream>>>(hs, WoT, bo, out);
}